// Round 8
// baseline (738.993 us; speedup 1.0000x reference)
//
#include <hip/hip_runtime.h>
#include <math.h>

#define N_NODES 100000
#define N_EDGES 3200000
#define F_IN 128
#define HID 16
#define C_OUT 10
#define NB 391        // ceil(N_NODES/256)
#define WIN 128       // nodes per window
#define NDIG 782      // ceil(N_NODES/WIN)
#define PNB2 512      // partition blocks
#define EPB 6250      // edges per partition block (exact: 3.2M/512)
#define SCN (NDIG * PNB2)      // 400384 = 1564 * 256 exactly
#define SB1 1564               // scan phase-1 blocks

typedef unsigned short u16;
typedef unsigned int u32;

__device__ __forceinline__ float bf2f(u16 u) {
    return __uint_as_float(((u32)u) << 16);
}
__device__ __forceinline__ u16 f2bf(float f) {
    u32 x = __float_as_uint(f);
    u32 r = (x + 0x7fffu + ((x >> 16) & 1u)) >> 16;  // round-nearest-even
    return (u16)r;
}

// ---------------- partition 1: per-block digit histogram (D=782, zero global atomics) ----------------
__global__ void k_pcnt(const int* __restrict__ col, int* __restrict__ blkhist) {
    __shared__ int h[NDIG];
    for (int i = threadIdx.x; i < NDIG; i += 256) h[i] = 0;
    __syncthreads();
    int lo = blockIdx.x * EPB, hi = lo + EPB;
    for (int e = lo + threadIdx.x; e < hi; e += 256)
        atomicAdd(&h[col[e] >> 7], 1);  // LDS atomic
    __syncthreads();
    for (int d = threadIdx.x; d < NDIG; d += 256)
        blkhist[d * PNB2 + blockIdx.x] = h[d];  // digit-major
}

// ---------------- partition 2: exclusive scan of blkhist[400384], in place ----------------
__global__ void k_s1(const int* __restrict__ blkhist, int* __restrict__ psum) {
    __shared__ int sm[256];
    int i = blockIdx.x * 256 + threadIdx.x;
    sm[threadIdx.x] = blkhist[i];
    __syncthreads();
    for (int off = 128; off > 0; off >>= 1) {
        if (threadIdx.x < off) sm[threadIdx.x] += sm[threadIdx.x + off];
        __syncthreads();
    }
    if (threadIdx.x == 0) psum[blockIdx.x] = sm[0];
}

__global__ void k_s2(int* __restrict__ psum) {  // exclusive scan of 1564 entries
    const int T = 1024;
    __shared__ int part[T];
    int t = threadIdx.x;
    int i0 = 2 * t, i1 = 2 * t + 1;
    int v0 = (i0 < SB1) ? psum[i0] : 0;
    int v1 = (i1 < SB1) ? psum[i1] : 0;
    part[t] = v0 + v1;
    __syncthreads();
    for (int off = 1; off < T; off <<= 1) {
        int v = part[t];
        int u = (t >= off) ? part[t - off] : 0;
        __syncthreads();
        part[t] = v + u;
        __syncthreads();
    }
    int run = (t > 0) ? part[t - 1] : 0;
    if (i0 < SB1) psum[i0] = run;
    if (i1 < SB1) psum[i1] = run + v0;
}

__global__ void k_s3(int* __restrict__ blkhist, const int* __restrict__ psum) {
    __shared__ int sm[256];
    int i = blockIdx.x * 256 + threadIdx.x;
    int t = threadIdx.x;
    int v = blkhist[i];
    sm[t] = v;
    __syncthreads();
    for (int off = 1; off < 256; off <<= 1) {
        int a = sm[t];
        int b = (t >= off) ? sm[t - off] : 0;
        __syncthreads();
        sm[t] = a + b;
        __syncthreads();
    }
    blkhist[i] = psum[blockIdx.x] + sm[t] - v;  // exclusive
}

// ---------------- partition 3: scatter edges to window-sorted staging ----------------
// entry: (c & 127) << 17 | src   (7 + 17 = 24 bits)
__global__ void k_pwrite(const int* __restrict__ row, const int* __restrict__ col,
                         const int* __restrict__ blkhist, u32* __restrict__ staging) {
    __shared__ int base[NDIG];
    __shared__ int lcur[NDIG];
    for (int i = threadIdx.x; i < NDIG; i += 256) {
        base[i] = blkhist[i * PNB2 + blockIdx.x];
        lcur[i] = 0;
    }
    __syncthreads();
    int lo = blockIdx.x * EPB, hi = lo + EPB;
    for (int e = lo + threadIdx.x; e < hi; e += 256) {
        int c = col[e];
        int d = c >> 7;
        int rank = atomicAdd(&lcur[d], 1);  // LDS atomic
        staging[base[d] + rank] = ((u32)(c & 127) << 17) | (u32)row[e];
    }
}

// ---------------- per-window degree -> dis (zero global atomics) ----------------
__global__ void k_wdeg(const u32* __restrict__ staging, const int* __restrict__ blkhist,
                       float* __restrict__ dis) {
    __shared__ int cnt[WIN];
    int w = blockIdx.x;
    if (threadIdx.x < WIN) cnt[threadIdx.x] = 0;
    __syncthreads();
    int start = blkhist[w * PNB2];
    int end = (w == NDIG - 1) ? N_EDGES : blkhist[(w + 1) * PNB2];
    for (int i = start + threadIdx.x; i < end; i += 256)
        atomicAdd(&cnt[staging[i] >> 17], 1);  // LDS atomic
    __syncthreads();
    if (threadIdx.x < WIN) {
        int node = w * WIN + threadIdx.x;
        if (node < N_NODES) dis[node] = rsqrtf(1.0f + (float)cnt[threadIdx.x]);
    }
}

// ---------------- layer 1 GEMM: h1s = (x @ W1) * dis[node]  (bf16) ----------------
__global__ void k_gemm1(const float* __restrict__ x, const float* __restrict__ W1,
                        const float* __restrict__ dis, u16* __restrict__ h1s) {
    __shared__ float Ws[F_IN * HID];  // 8 KB
    for (int t = threadIdx.x; t < F_IN * HID; t += blockDim.x) Ws[t] = W1[t];
    __syncthreads();

    int node = blockIdx.x * blockDim.x + threadIdx.x;
    if (node >= N_NODES) return;

    float acc[HID];
#pragma unroll
    for (int j = 0; j < HID; j++) acc[j] = 0.f;

    const float4* xr = (const float4*)(x + (size_t)node * F_IN);
#pragma unroll 2
    for (int k4 = 0; k4 < F_IN / 4; k4++) {
        float4 v = xr[k4];
        float xv[4] = {v.x, v.y, v.z, v.w};
#pragma unroll
        for (int kk = 0; kk < 4; kk++) {
            const float4* wr = (const float4*)(Ws + (k4 * 4 + kk) * HID);
            float4 w0 = wr[0], w1 = wr[1], w2 = wr[2], w3 = wr[3];
            float xs = xv[kk];
            acc[0]  += xs * w0.x; acc[1]  += xs * w0.y; acc[2]  += xs * w0.z; acc[3]  += xs * w0.w;
            acc[4]  += xs * w1.x; acc[5]  += xs * w1.y; acc[6]  += xs * w1.z; acc[7]  += xs * w1.w;
            acc[8]  += xs * w2.x; acc[9]  += xs * w2.y; acc[10] += xs * w2.z; acc[11] += xs * w2.w;
            acc[12] += xs * w3.x; acc[13] += xs * w3.y; acc[14] += xs * w3.z; acc[15] += xs * w3.w;
        }
    }

    float d = dis[node];
    u32 p[8];
#pragma unroll
    for (int i = 0; i < 8; i++)
        p[i] = (u32)f2bf(acc[2 * i] * d) | ((u32)f2bf(acc[2 * i + 1] * d) << 16);
    u32* dst = (u32*)(h1s + (size_t)node * HID);
#pragma unroll
    for (int i = 0; i < 8; i++) dst[i] = p[i];
}

// ---------------- aggregate layer 1: window-LDS accumulation, zero global atomics ----------------
// One block per 128-node window. acc stride 17 floats (bank-spread).
__global__ void k_agg1(const u32* __restrict__ staging, const int* __restrict__ blkhist,
                       const float* __restrict__ dis, const u16* __restrict__ h1s,
                       u16* __restrict__ agg1) {
    __shared__ float acc[WIN * 17];
    int w = blockIdx.x;
    for (int i = threadIdx.x; i < WIN * 17; i += 256) acc[i] = 0.f;
    __syncthreads();

    int start = blkhist[w * PNB2];
    int end = (w == NDIG - 1) ? N_EDGES : blkhist[(w + 1) * PNB2];
    int eg = threadIdx.x >> 3;   // 0..31 edge slots
    int f  = threadIdx.x & 7;    // feature pair
    const u32* h32 = (const u32*)h1s;
    for (int i = start + eg; i < end; i += 32) {
        u32 e = staging[i];              // 8 lanes broadcast
        int cl = (int)(e >> 17);
        int s  = (int)(e & 0x1FFFFu);
        u32 hh = h32[(size_t)s * 8 + f]; // 8 lanes -> one 32B row
        atomicAdd(&acc[cl * 17 + 2 * f], bf2f((u16)(hh & 0xffff)));
        atomicAdd(&acc[cl * 17 + 2 * f + 1], bf2f((u16)(hh >> 16)));
    }
    __syncthreads();

    // epilogue: 2 threads per node, 4 u32 (8 features) each
    int half = threadIdx.x >> 7;         // 0/1
    int nl   = threadIdx.x & 127;
    int node = w * WIN + nl;
    if (node < N_NODES) {
        float dc = dis[node];
        u32* dst = (u32*)(agg1 + (size_t)node * HID);
#pragma unroll
        for (int j = 0; j < 4; j++) {
            int k = half * 8 + 2 * j;
            u32 selfv = h32[(size_t)node * 8 + half * 4 + j];
            float v0 = (acc[nl * 17 + k] + bf2f((u16)(selfv & 0xffff))) * dc;
            float v1 = (acc[nl * 17 + k + 1] + bf2f((u16)(selfv >> 16))) * dc;
            dst[half * 4 + j] = (u32)f2bf(v0) | ((u32)f2bf(v1) << 16);
        }
    }
}

// ---------------- layer 2: h = relu(agg1+b1); h2s = (h @ W2) * dis  (bf16, padded to 16) ----------------
__global__ void k_layer2(const u16* __restrict__ agg1, const float* __restrict__ b1,
                         const float* __restrict__ W2, const float* __restrict__ dis,
                         u16* __restrict__ h2s) {
    __shared__ float Ws[HID * C_OUT];
    __shared__ float b1s[HID];
    if (threadIdx.x < HID * C_OUT) Ws[threadIdx.x] = W2[threadIdx.x];
    if (threadIdx.x < HID) b1s[threadIdx.x] = b1[threadIdx.x];
    __syncthreads();

    int node = blockIdx.x * blockDim.x + threadIdx.x;
    if (node >= N_NODES) return;

    const uint4* ar = (const uint4*)(agg1 + (size_t)node * HID);
    uint4 q0 = ar[0], q1 = ar[1];
    u32 qs[8] = {q0.x, q0.y, q0.z, q0.w, q1.x, q1.y, q1.z, q1.w};

    float acc[C_OUT];
#pragma unroll
    for (int k = 0; k < C_OUT; k++) acc[k] = 0.f;

#pragma unroll
    for (int i = 0; i < 8; i++) {
        u32 q = qs[i];
        float v0 = bf2f((u16)(q & 0xffff));
        float v1 = bf2f((u16)(q >> 16));
        int j0 = 2 * i, j1 = 2 * i + 1;
        float h0 = fmaxf(v0 + b1s[j0], 0.f);
        float h1v = fmaxf(v1 + b1s[j1], 0.f);
#pragma unroll
        for (int k = 0; k < C_OUT; k++) acc[k] += h0 * Ws[j0 * C_OUT + k] + h1v * Ws[j1 * C_OUT + k];
    }

    float d = dis[node];
    u32 p[8];
#pragma unroll
    for (int i = 0; i < 5; i++)
        p[i] = (u32)f2bf(acc[2 * i] * d) | ((u32)f2bf(acc[2 * i + 1] * d) << 16);
    p[5] = 0; p[6] = 0; p[7] = 0;  // pad features 10..15
    u32* dst = (u32*)(h2s + (size_t)node * HID);
#pragma unroll
    for (int i = 0; i < 8; i++) dst[i] = p[i];
}

// ---------------- aggregate layer 2 -> d_out (fp32) ----------------
__global__ void k_agg2(const u32* __restrict__ staging, const int* __restrict__ blkhist,
                       const float* __restrict__ dis, const u16* __restrict__ h2s,
                       float* __restrict__ agg2) {
    __shared__ float acc[WIN * 17];
    int w = blockIdx.x;
    for (int i = threadIdx.x; i < WIN * 17; i += 256) acc[i] = 0.f;
    __syncthreads();

    int start = blkhist[w * PNB2];
    int end = (w == NDIG - 1) ? N_EDGES : blkhist[(w + 1) * PNB2];
    int eg = threadIdx.x >> 3;
    int f  = threadIdx.x & 7;
    const u32* h32 = (const u32*)h2s;
    for (int i = start + eg; i < end; i += 32) {
        u32 e = staging[i];
        int cl = (int)(e >> 17);
        int s  = (int)(e & 0x1FFFFu);
        if (f < 5) {  // features 10..15 are zero padding
            u32 hh = h32[(size_t)s * 8 + f];
            atomicAdd(&acc[cl * 17 + 2 * f], bf2f((u16)(hh & 0xffff)));
            atomicAdd(&acc[cl * 17 + 2 * f + 1], bf2f((u16)(hh >> 16)));
        }
    }
    __syncthreads();

    // epilogue: half0 thread -> features 0..7, half1 -> 8,9
    int half = threadIdx.x >> 7;
    int nl   = threadIdx.x & 127;
    int node = w * WIN + nl;
    if (node < N_NODES) {
        float dc = dis[node];
        float* dst = agg2 + (size_t)node * C_OUT;
        int k0 = half * 8;
        int kn = half ? 2 : 8;
        for (int j = 0; j < kn; j++) {
            int k = k0 + j;
            u32 selfv = h32[(size_t)node * 8 + (k >> 1)];
            u16 sh = (k & 1) ? (u16)(selfv >> 16) : (u16)(selfv & 0xffff);
            dst[k] = (acc[nl * 17 + k] + bf2f(sh)) * dc;
        }
    }
}

// ---------------- final: log_softmax in place on d_out ----------------
__global__ void k_final(float* __restrict__ agg2, const float* __restrict__ b2) {
    __shared__ float b2s[C_OUT];
    if (threadIdx.x < C_OUT) b2s[threadIdx.x] = b2[threadIdx.x];
    __syncthreads();

    int i = blockIdx.x * blockDim.x + threadIdx.x;
    if (i >= N_NODES) return;

    float* ar = agg2 + (size_t)i * C_OUT;
    float v[C_OUT];
    float m = -1e30f;
#pragma unroll
    for (int k = 0; k < C_OUT; k++) {
        v[k] = ar[k] + b2s[k];
        m = fmaxf(m, v[k]);
    }
    float s = 0.f;
#pragma unroll
    for (int k = 0; k < C_OUT; k++) s += expf(v[k] - m);
    float ls = logf(s) + m;
#pragma unroll
    for (int k = 0; k < C_OUT; k++) ar[k] = v[k] - ls;
}

// ---------------- launch ----------------
extern "C" void kernel_launch(void* const* d_in, const int* in_sizes, int n_in,
                              void* d_out, int out_size, void* d_ws, size_t ws_size,
                              hipStream_t stream) {
    const float* x  = (const float*)d_in[0];
    const int*   ei = (const int*)d_in[1];
    const float* W1 = (const float*)d_in[2];
    const float* b1 = (const float*)d_in[3];
    const float* W2 = (const float*)d_in[4];
    const float* b2 = (const float*)d_in[5];
    float* out = (float*)d_out;

    const int* row = ei;            // sources
    const int* col = ei + N_EDGES;  // targets

    // workspace (~18.0 MB). agg1 lives in d_out (bf16, 3.2MB of 4MB), dead
    // before k_agg2 rewrites d_out as fp32.
    char* ws = (char*)d_ws;
    float* dis     = (float*)(ws);                    // 400000 B
    int*   blkhist = (int*)(ws + 400000);             // 400384 ints = 1601536 B
    int*   psum    = (int*)(ws + 2001536);            // 1564 ints
    u32*   staging = (u32*)(ws + 2007808);            // 12.8 MB
    u16*   h1s     = (u16*)(ws + 14807808);           // 3.2 MB
    u16*   h2s     = (u16*)(ws + 14807808);           // alias (h1s dead after agg1)
    u16*   agg1    = (u16*)d_out;                     // 3.2 MB scratch in d_out
    float* agg2    = out;                             // finalized in place

    const int B = 256;
    int gN = (N_NODES + B - 1) / B;  // 391

    // deterministic window partition (zero global atomics)
    k_pcnt  <<<PNB2, B, 0, stream>>>(col, blkhist);
    k_s1    <<<SB1, B, 0, stream>>>(blkhist, psum);
    k_s2    <<<1, 1024, 0, stream>>>(psum);
    k_s3    <<<SB1, B, 0, stream>>>(blkhist, psum);
    k_pwrite<<<PNB2, B, 0, stream>>>(row, col, blkhist, staging);
    k_wdeg  <<<NDIG, B, 0, stream>>>(staging, blkhist, dis);
    // dense pipeline
    k_gemm1 <<<gN, B, 0, stream>>>(x, W1, dis, h1s);
    k_agg1  <<<NDIG, B, 0, stream>>>(staging, blkhist, dis, h1s, agg1);
    k_layer2<<<gN, B, 0, stream>>>(agg1, b1, W2, dis, h2s);
    k_agg2  <<<NDIG, B, 0, stream>>>(staging, blkhist, dis, h2s, agg2);
    k_final <<<gN, B, 0, stream>>>(agg2, b2);
}

// Round 9
// 260.859 us; speedup vs baseline: 2.8329x; 2.8329x over previous
//
#include <hip/hip_runtime.h>
#include <math.h>

#define N_NODES 100000
#define N_EDGES 3200000
#define F_IN 128
#define HID 16
#define C_OUT 10
#define WIN 128       // nodes per window
#define NDIG 782      // ceil(N_NODES/WIN)
#define PNB2 512      // partition blocks
#define EPB 6250      // edges per partition block (exact: 3.2M/512)
#define SB1 1564      // scan phase-1 blocks (NDIG*PNB2 = 400384 = 1564*256)
#define MAXE 28       // max staged entries per thread per window (7168 cap vs mean 4090, ~48 sigma)

typedef unsigned short u16;
typedef unsigned int u32;

__device__ __forceinline__ float bf2f(u16 u) {
    return __uint_as_float(((u32)u) << 16);
}
__device__ __forceinline__ u16 f2bf(float f) {
    u32 x = __float_as_uint(f);
    u32 r = (x + 0x7fffu + ((x >> 16) & 1u)) >> 16;  // round-nearest-even
    return (u16)r;
}

// ---------------- partition 1: per-block window histogram (zero global atomics) ----------------
__global__ void k_pcnt(const int* __restrict__ col, int* __restrict__ blkhist) {
    __shared__ int h[NDIG];
    for (int i = threadIdx.x; i < NDIG; i += 256) h[i] = 0;
    __syncthreads();
    int lo = blockIdx.x * EPB, hi = lo + EPB;
    for (int e = lo + threadIdx.x; e < hi; e += 256)
        atomicAdd(&h[col[e] >> 7], 1);  // LDS atomic
    __syncthreads();
    for (int d = threadIdx.x; d < NDIG; d += 256)
        blkhist[d * PNB2 + blockIdx.x] = h[d];  // digit-major
}

// ---------------- partition 2: exclusive scan of blkhist[400384] ----------------
__global__ void k_s1(const int* __restrict__ blkhist, int* __restrict__ psum) {
    __shared__ int sm[256];
    int i = blockIdx.x * 256 + threadIdx.x;
    sm[threadIdx.x] = blkhist[i];
    __syncthreads();
    for (int off = 128; off > 0; off >>= 1) {
        if (threadIdx.x < off) sm[threadIdx.x] += sm[threadIdx.x + off];
        __syncthreads();
    }
    if (threadIdx.x == 0) psum[blockIdx.x] = sm[0];
}

__global__ void k_s2(int* __restrict__ psum) {  // exclusive scan of 1564 entries
    const int T = 1024;
    __shared__ int part[T];
    int t = threadIdx.x;
    int i0 = 2 * t, i1 = 2 * t + 1;
    int v0 = (i0 < SB1) ? psum[i0] : 0;
    int v1 = (i1 < SB1) ? psum[i1] : 0;
    part[t] = v0 + v1;
    __syncthreads();
    for (int off = 1; off < T; off <<= 1) {
        int v = part[t];
        int u = (t >= off) ? part[t - off] : 0;
        __syncthreads();
        part[t] = v + u;
        __syncthreads();
    }
    int run = (t > 0) ? part[t - 1] : 0;
    if (i0 < SB1) psum[i0] = run;
    if (i1 < SB1) psum[i1] = run + v0;
}

__global__ void k_s3(int* __restrict__ blkhist, const int* __restrict__ psum) {
    __shared__ int sm[256];
    int i = blockIdx.x * 256 + threadIdx.x;
    int t = threadIdx.x;
    int v = blkhist[i];
    sm[t] = v;
    __syncthreads();
    for (int off = 1; off < 256; off <<= 1) {
        int a = sm[t];
        int b = (t >= off) ? sm[t - off] : 0;
        __syncthreads();
        sm[t] = a + b;
        __syncthreads();
    }
    blkhist[i] = psum[blockIdx.x] + sm[t] - v;  // exclusive
}

// ---------------- partition 3: scatter edges to window-sorted staging ----------------
// entry: (c & 127) << 17 | src   (7 + 17 = 24 bits)
__global__ void k_pwrite(const int* __restrict__ row, const int* __restrict__ col,
                         const int* __restrict__ blkhist, u32* __restrict__ staging) {
    __shared__ int base[NDIG];
    __shared__ int lcur[NDIG];
    for (int i = threadIdx.x; i < NDIG; i += 256) {
        base[i] = blkhist[i * PNB2 + blockIdx.x];
        lcur[i] = 0;
    }
    __syncthreads();
    int lo = blockIdx.x * EPB, hi = lo + EPB;
    for (int e = lo + threadIdx.x; e < hi; e += 256) {
        int c = col[e];
        int d = c >> 7;
        int rank = atomicAdd(&lcur[d], 1);  // LDS atomic
        staging[base[d] + rank] = ((u32)(c & 127) << 17) | (u32)row[e];
    }
}

// ---------------- node-sort each window IN PLACE; emit offs + dis ----------------
// One block per window (~4090 edges). Entries read to registers, LDS hist ->
// 128-wide scan -> in-place scatter. staging becomes a node-sorted CSR whose
// low 17 bits are src. Zero global atomics.
__global__ void k_csr(u32* staging, const int* __restrict__ blkhist,
                      int* __restrict__ offs, float* __restrict__ dis) {
    __shared__ int cnt[WIN];
    __shared__ int base[WIN];
    int w = blockIdx.x;
    if (threadIdx.x < WIN) cnt[threadIdx.x] = 0;
    __syncthreads();
    int start = blkhist[w * PNB2];
    int end = (w == NDIG - 1) ? N_EDGES : blkhist[(w + 1) * PNB2];
    u32 buf[MAXE];
    int n = 0;
#pragma unroll
    for (int k = 0; k < MAXE; k++) {
        int i = start + k * 256 + (int)threadIdx.x;
        if (i < end) {
            u32 e = staging[i];
            buf[k] = e;
            n = k + 1;
            atomicAdd(&cnt[e >> 17], 1);  // LDS atomic
        }
    }
    __syncthreads();
    // inclusive scan of cnt -> base
    if (threadIdx.x < WIN) base[threadIdx.x] = cnt[threadIdx.x];
    __syncthreads();
    for (int off = 1; off < WIN; off <<= 1) {
        int v = 0;
        if (threadIdx.x < WIN) {
            v = base[threadIdx.x];
            if ((int)threadIdx.x >= off) v += base[threadIdx.x - off];
        }
        __syncthreads();
        if (threadIdx.x < WIN) base[threadIdx.x] = v;
        __syncthreads();
    }
    // convert to exclusive, write offs/dis
    if (threadIdx.x < WIN) {
        int excl = base[threadIdx.x] - cnt[threadIdx.x];
        base[threadIdx.x] = excl;
        int node = w * WIN + (int)threadIdx.x;
        if (node < N_NODES) {
            offs[node] = start + excl;
            dis[node] = rsqrtf(1.0f + (float)cnt[threadIdx.x]);
        }
    }
    if (w == 0 && threadIdx.x == 0) offs[N_NODES] = N_EDGES;
    __syncthreads();
    if (threadIdx.x < WIN) cnt[threadIdx.x] = 0;  // reuse as cursor
    __syncthreads();
#pragma unroll
    for (int k = 0; k < MAXE; k++) {
        if (k < n) {
            u32 e = buf[k];
            int cl = (int)(e >> 17);
            int rank = atomicAdd(&cnt[cl], 1);  // LDS atomic
            staging[start + base[cl] + rank] = e;
        }
    }
}

// ---------------- layer 1 GEMM: h1s = (x @ W1) * dis[node]  (bf16) ----------------
__global__ void k_gemm1(const float* __restrict__ x, const float* __restrict__ W1,
                        const float* __restrict__ dis, u16* __restrict__ h1s) {
    __shared__ float Ws[F_IN * HID];  // 8 KB
    for (int t = threadIdx.x; t < F_IN * HID; t += blockDim.x) Ws[t] = W1[t];
    __syncthreads();

    int node = blockIdx.x * blockDim.x + threadIdx.x;
    if (node >= N_NODES) return;

    float acc[HID];
#pragma unroll
    for (int j = 0; j < HID; j++) acc[j] = 0.f;

    const float4* xr = (const float4*)(x + (size_t)node * F_IN);
#pragma unroll 2
    for (int k4 = 0; k4 < F_IN / 4; k4++) {
        float4 v = xr[k4];
        float xv[4] = {v.x, v.y, v.z, v.w};
#pragma unroll
        for (int kk = 0; kk < 4; kk++) {
            const float4* wr = (const float4*)(Ws + (k4 * 4 + kk) * HID);
            float4 w0 = wr[0], w1 = wr[1], w2 = wr[2], w3 = wr[3];
            float xs = xv[kk];
            acc[0]  += xs * w0.x; acc[1]  += xs * w0.y; acc[2]  += xs * w0.z; acc[3]  += xs * w0.w;
            acc[4]  += xs * w1.x; acc[5]  += xs * w1.y; acc[6]  += xs * w1.z; acc[7]  += xs * w1.w;
            acc[8]  += xs * w2.x; acc[9]  += xs * w2.y; acc[10] += xs * w2.z; acc[11] += xs * w2.w;
            acc[12] += xs * w3.x; acc[13] += xs * w3.y; acc[14] += xs * w3.z; acc[15] += xs * w3.w;
        }
    }

    float d = dis[node];
    u32 p[8];
#pragma unroll
    for (int i = 0; i < 8; i++)
        p[i] = (u32)f2bf(acc[2 * i] * d) | ((u32)f2bf(acc[2 * i + 1] * d) << 16);
    u32* dst = (u32*)(h1s + (size_t)node * HID);
#pragma unroll
    for (int i = 0; i < 8; i++) dst[i] = p[i];
}

// ---------------- gather layer 1: 8 lanes/node, uint4 CSR reads (4 h-rows in flight) ----------------
__global__ void k_gather1(const int* __restrict__ offs, const u32* __restrict__ csr,
                          const float* __restrict__ dis, const u16* __restrict__ h1s,
                          u16* __restrict__ agg1) {
    int t = blockIdx.x * 256 + threadIdx.x;   // exactly N_NODES*8 threads
    int node = t >> 3;
    int f2 = t & 7;
    const u32* hb = (const u32*)h1s;
    u32 v = hb[(size_t)node * 8 + f2];        // self loop (already * dis[node])
    float a0 = bf2f((u16)(v & 0xffff));
    float a1 = bf2f((u16)(v >> 16));
    int s0 = offs[node], s1 = offs[node + 1];
    int j = s0;
    for (; j < s1 && (j & 3); j++) {
        int s = (int)(csr[j] & 0x1FFFFu);
        u32 w = hb[(size_t)s * 8 + f2];
        a0 += bf2f((u16)(w & 0xffff));
        a1 += bf2f((u16)(w >> 16));
    }
    for (; j + 4 <= s1; j += 4) {
        uint4 ss = *(const uint4*)(csr + j);  // broadcast across the node's 8 lanes
        u32 w0 = hb[(size_t)(ss.x & 0x1FFFFu) * 8 + f2];
        u32 w1 = hb[(size_t)(ss.y & 0x1FFFFu) * 8 + f2];
        u32 w2 = hb[(size_t)(ss.z & 0x1FFFFu) * 8 + f2];
        u32 w3 = hb[(size_t)(ss.w & 0x1FFFFu) * 8 + f2];
        a0 += bf2f((u16)(w0 & 0xffff)); a1 += bf2f((u16)(w0 >> 16));
        a0 += bf2f((u16)(w1 & 0xffff)); a1 += bf2f((u16)(w1 >> 16));
        a0 += bf2f((u16)(w2 & 0xffff)); a1 += bf2f((u16)(w2 >> 16));
        a0 += bf2f((u16)(w3 & 0xffff)); a1 += bf2f((u16)(w3 >> 16));
    }
    for (; j < s1; j++) {
        int s = (int)(csr[j] & 0x1FFFFu);
        u32 w = hb[(size_t)s * 8 + f2];
        a0 += bf2f((u16)(w & 0xffff));
        a1 += bf2f((u16)(w >> 16));
    }
    float dc = dis[node];
    ((u32*)agg1)[(size_t)node * 8 + f2] =
        (u32)f2bf(a0 * dc) | ((u32)f2bf(a1 * dc) << 16);
}

// ---------------- layer 2: h = relu(agg1+b1); h2s = (h @ W2) * dis  (bf16, padded to 16) ----------------
__global__ void k_layer2(const u16* __restrict__ agg1, const float* __restrict__ b1,
                         const float* __restrict__ W2, const float* __restrict__ dis,
                         u16* __restrict__ h2s) {
    __shared__ float Ws[HID * C_OUT];
    __shared__ float b1s[HID];
    if (threadIdx.x < HID * C_OUT) Ws[threadIdx.x] = W2[threadIdx.x];
    if (threadIdx.x < HID) b1s[threadIdx.x] = b1[threadIdx.x];
    __syncthreads();

    int node = blockIdx.x * blockDim.x + threadIdx.x;
    if (node >= N_NODES) return;

    const uint4* ar = (const uint4*)(agg1 + (size_t)node * HID);
    uint4 q0 = ar[0], q1 = ar[1];
    u32 qs[8] = {q0.x, q0.y, q0.z, q0.w, q1.x, q1.y, q1.z, q1.w};

    float acc[C_OUT];
#pragma unroll
    for (int k = 0; k < C_OUT; k++) acc[k] = 0.f;

#pragma unroll
    for (int i = 0; i < 8; i++) {
        u32 q = qs[i];
        float v0 = bf2f((u16)(q & 0xffff));
        float v1 = bf2f((u16)(q >> 16));
        int j0 = 2 * i, j1 = 2 * i + 1;
        float h0 = fmaxf(v0 + b1s[j0], 0.f);
        float h1v = fmaxf(v1 + b1s[j1], 0.f);
#pragma unroll
        for (int k = 0; k < C_OUT; k++) acc[k] += h0 * Ws[j0 * C_OUT + k] + h1v * Ws[j1 * C_OUT + k];
    }

    float d = dis[node];
    u32 p[8];
#pragma unroll
    for (int i = 0; i < 5; i++)
        p[i] = (u32)f2bf(acc[2 * i] * d) | ((u32)f2bf(acc[2 * i + 1] * d) << 16);
    p[5] = 0; p[6] = 0; p[7] = 0;  // pad features 10..15
    u32* dst = (u32*)(h2s + (size_t)node * HID);
#pragma unroll
    for (int i = 0; i < 8; i++) dst[i] = p[i];
}

// ---------------- gather layer 2 -> d_out (fp32) ----------------
__global__ void k_gather2(const int* __restrict__ offs, const u32* __restrict__ csr,
                          const float* __restrict__ dis, const u16* __restrict__ h2s,
                          float* __restrict__ agg2) {
    int t = blockIdx.x * 256 + threadIdx.x;
    int node = t >> 3;
    int f2 = t & 7;
    if (f2 >= 5) return;  // features 10..15 are zero padding
    const u32* hb = (const u32*)h2s;
    u32 v = hb[(size_t)node * 8 + f2];
    float a0 = bf2f((u16)(v & 0xffff));
    float a1 = bf2f((u16)(v >> 16));
    int s0 = offs[node], s1 = offs[node + 1];
    int j = s0;
    for (; j < s1 && (j & 3); j++) {
        int s = (int)(csr[j] & 0x1FFFFu);
        u32 w = hb[(size_t)s * 8 + f2];
        a0 += bf2f((u16)(w & 0xffff));
        a1 += bf2f((u16)(w >> 16));
    }
    for (; j + 4 <= s1; j += 4) {
        uint4 ss = *(const uint4*)(csr + j);
        u32 w0 = hb[(size_t)(ss.x & 0x1FFFFu) * 8 + f2];
        u32 w1 = hb[(size_t)(ss.y & 0x1FFFFu) * 8 + f2];
        u32 w2 = hb[(size_t)(ss.z & 0x1FFFFu) * 8 + f2];
        u32 w3 = hb[(size_t)(ss.w & 0x1FFFFu) * 8 + f2];
        a0 += bf2f((u16)(w0 & 0xffff)); a1 += bf2f((u16)(w0 >> 16));
        a0 += bf2f((u16)(w1 & 0xffff)); a1 += bf2f((u16)(w1 >> 16));
        a0 += bf2f((u16)(w2 & 0xffff)); a1 += bf2f((u16)(w2 >> 16));
        a0 += bf2f((u16)(w3 & 0xffff)); a1 += bf2f((u16)(w3 >> 16));
    }
    for (; j < s1; j++) {
        int s = (int)(csr[j] & 0x1FFFFu);
        u32 w = hb[(size_t)s * 8 + f2];
        a0 += bf2f((u16)(w & 0xffff));
        a1 += bf2f((u16)(w >> 16));
    }
    float dc = dis[node];
    float2 o = make_float2(a0 * dc, a1 * dc);
    *(float2*)(agg2 + (size_t)node * C_OUT + 2 * f2) = o;  // 8B-aligned
}

// ---------------- final: log_softmax in place on d_out ----------------
__global__ void k_final(float* __restrict__ agg2, const float* __restrict__ b2) {
    __shared__ float b2s[C_OUT];
    if (threadIdx.x < C_OUT) b2s[threadIdx.x] = b2[threadIdx.x];
    __syncthreads();

    int i = blockIdx.x * blockDim.x + threadIdx.x;
    if (i >= N_NODES) return;

    float* ar = agg2 + (size_t)i * C_OUT;
    float v[C_OUT];
    float m = -1e30f;
#pragma unroll
    for (int k = 0; k < C_OUT; k++) {
        v[k] = ar[k] + b2s[k];
        m = fmaxf(m, v[k]);
    }
    float s = 0.f;
#pragma unroll
    for (int k = 0; k < C_OUT; k++) s += expf(v[k] - m);
    float ls = logf(s) + m;
#pragma unroll
    for (int k = 0; k < C_OUT; k++) ar[k] = v[k] - ls;
}

// ---------------- launch ----------------
extern "C" void kernel_launch(void* const* d_in, const int* in_sizes, int n_in,
                              void* d_out, int out_size, void* d_ws, size_t ws_size,
                              hipStream_t stream) {
    const float* x  = (const float*)d_in[0];
    const int*   ei = (const int*)d_in[1];
    const float* W1 = (const float*)d_in[2];
    const float* b1 = (const float*)d_in[3];
    const float* W2 = (const float*)d_in[4];
    const float* b2 = (const float*)d_in[5];
    float* out = (float*)d_out;

    const int* row = ei;            // sources
    const int* col = ei + N_EDGES;  // targets

    // workspace (~18.4 MB). agg1 (bf16, 3.2MB) lives in d_out, dead before
    // k_gather2 rewrites d_out as fp32.
    char* ws = (char*)d_ws;
    float* dis     = (float*)(ws);                    // 400000 B
    int*   offs    = (int*)(ws + 400000);             // N+1 ints
    int*   blkhist = (int*)(ws + 800016);             // 400384 ints = 1601536 B
    int*   psum    = (int*)(ws + 2401552);            // 1564 ints
    u32*   staging = (u32*)(ws + 2407808);            // 12.8 MB (16B aligned), becomes CSR
    u16*   h1s     = (u16*)(ws + 15207808);           // 3.2 MB
    u16*   h2s     = (u16*)(ws + 15207808);           // alias (h1s dead after gather1)
    u16*   agg1    = (u16*)d_out;                     // 3.2 MB scratch in d_out
    float* agg2    = out;                             // finalized in place

    const int B = 256;
    int gN  = (N_NODES + B - 1) / B;            // 391
    int gN8 = (N_NODES * 8) / B;                // 3125 exact

    // deterministic window partition + in-window node sort (zero global atomics)
    k_pcnt  <<<PNB2, B, 0, stream>>>(col, blkhist);
    k_s1    <<<SB1, B, 0, stream>>>(blkhist, psum);
    k_s2    <<<1, 1024, 0, stream>>>(psum);
    k_s3    <<<SB1, B, 0, stream>>>(blkhist, psum);
    k_pwrite<<<PNB2, B, 0, stream>>>(row, col, blkhist, staging);
    k_csr   <<<NDIG, B, 0, stream>>>(staging, blkhist, offs, dis);
    // dense pipeline
    k_gemm1 <<<gN, B, 0, stream>>>(x, W1, dis, h1s);
    k_gather1<<<gN8, B, 0, stream>>>(offs, staging, dis, h1s, agg1);
    k_layer2<<<gN, B, 0, stream>>>(agg1, b1, W2, dis, h2s);
    k_gather2<<<gN8, B, 0, stream>>>(offs, staging, dis, h2s, agg2);
    k_final <<<gN, B, 0, stream>>>(agg2, b2);
}

// Round 10
// 251.297 us; speedup vs baseline: 2.9407x; 1.0381x over previous
//
#include <hip/hip_runtime.h>
#include <math.h>

#define N_NODES 100000
#define N_EDGES 3200000
#define F_IN 128
#define HID 16
#define C_OUT 10
#define WIN 256       // nodes per window
#define NDIG 391      // ceil(N_NODES/WIN)
#define PNB2 512      // partition blocks
#define EPB 6250      // edges per partition block (exact: 3.2M/512)
#define SCN (NDIG * PNB2)   // 200192 = 782 * 256
#define SB1 782       // scan phase-1 blocks
#define MAXE 40       // per-thread staged entries in k_csr (cap 10240 vs mean 8184, ~22 sigma)

typedef unsigned short u16;
typedef unsigned int u32;

__device__ __forceinline__ float bf2f(u16 u) {
    return __uint_as_float(((u32)u) << 16);
}
__device__ __forceinline__ u16 f2bf(float f) {
    u32 x = __float_as_uint(f);
    u32 r = (x + 0x7fffu + ((x >> 16) & 1u)) >> 16;  // round-nearest-even
    return (u16)r;
}

// ---------------- partition 1: per-block window histogram (zero global atomics) ----------------
__global__ void k_pcnt(const int* __restrict__ col, int* __restrict__ blkhistA) {
    __shared__ int h[NDIG];
    for (int i = threadIdx.x; i < NDIG; i += 256) h[i] = 0;
    __syncthreads();
    int lo = blockIdx.x * EPB, hi = lo + EPB;
    for (int e = lo + threadIdx.x; e < hi; e += 256)
        atomicAdd(&h[col[e] >> 8], 1);  // LDS atomic
    __syncthreads();
    for (int d = threadIdx.x; d < NDIG; d += 256)
        blkhistA[d * PNB2 + blockIdx.x] = h[d];  // digit-major, raw (kept!)
}

// ---------------- partition 2: exclusive scan blkhistA -> blkhistB ----------------
__global__ void k_s1(const int* __restrict__ blkhistA, int* __restrict__ psum) {
    __shared__ int sm[256];
    int i = blockIdx.x * 256 + threadIdx.x;
    sm[threadIdx.x] = blkhistA[i];
    __syncthreads();
    for (int off = 128; off > 0; off >>= 1) {
        if (threadIdx.x < off) sm[threadIdx.x] += sm[threadIdx.x + off];
        __syncthreads();
    }
    if (threadIdx.x == 0) psum[blockIdx.x] = sm[0];
}

__global__ void k_s2(int* __restrict__ psum) {  // exclusive scan of 782 entries
    const int T = 1024;
    __shared__ int part[T];
    int t = threadIdx.x;
    int v0 = (t < SB1) ? psum[t] : 0;
    part[t] = v0;
    __syncthreads();
    for (int off = 1; off < T; off <<= 1) {
        int v = part[t];
        int u = (t >= off) ? part[t - off] : 0;
        __syncthreads();
        part[t] = v + u;
        __syncthreads();
    }
    if (t < SB1) psum[t] = part[t] - v0;  // exclusive
}

__global__ void k_s3(const int* __restrict__ blkhistA, const int* __restrict__ psum,
                     int* __restrict__ blkhistB) {
    __shared__ int sm[256];
    int i = blockIdx.x * 256 + threadIdx.x;
    int t = threadIdx.x;
    int v = blkhistA[i];
    sm[t] = v;
    __syncthreads();
    for (int off = 1; off < 256; off <<= 1) {
        int a = sm[t];
        int b = (t >= off) ? sm[t - off] : 0;
        __syncthreads();
        sm[t] = a + b;
        __syncthreads();
    }
    blkhistB[i] = psum[blockIdx.x] + sm[t] - v;  // exclusive global offset
}

// ---------------- partition 3: LDS-sorted scatter -> run-coalesced staging writes ----------------
// entry: (c & 255) << 17 | src   (8 + 17 = 25 bits).  512 threads/block.
__global__ void k_pwrite(const int* __restrict__ row, const int* __restrict__ col,
                         const int* __restrict__ blkhistA, const int* __restrict__ blkhistB,
                         u32* __restrict__ staging) {
    __shared__ u32 sorted[EPB];     // 25000 B
    __shared__ u16 dwin[EPB];       // 12500 B
    __shared__ int gbase[NDIG];
    __shared__ int lbase[NDIG];
    __shared__ int lcur[NDIG];
    __shared__ int scan[512];

    int t = threadIdx.x;
    int b = blockIdx.x;
    // load raw hist + global base for this block
    int hv = 0;
    if (t < NDIG) {
        hv = blkhistA[t * PNB2 + b];
        gbase[t] = blkhistB[t * PNB2 + b];
        lcur[t] = 0;
    }
    scan[t] = hv;
    __syncthreads();
    for (int off = 1; off < 512; off <<= 1) {
        int v = scan[t];
        int u = (t >= off) ? scan[t - off] : 0;
        __syncthreads();
        scan[t] = v + u;
        __syncthreads();
    }
    if (t < NDIG) lbase[t] = scan[t] - hv;  // exclusive local offset
    __syncthreads();

    // scatter edges into LDS, sorted by window
    int lo = b * EPB, hi = lo + EPB;
    for (int e = lo + t; e < hi; e += 512) {
        int c = col[e];
        int d = c >> 8;
        int rank = atomicAdd(&lcur[d], 1);  // LDS atomic
        int pos = lbase[d] + rank;
        sorted[pos] = ((u32)(c & 255) << 17) | (u32)row[e];
        dwin[pos] = (u16)d;
    }
    __syncthreads();

    // copy out: consecutive i -> consecutive dest within each window run
    for (int i = t; i < EPB; i += 512) {
        int d = dwin[i];
        staging[gbase[d] + (i - lbase[d])] = sorted[i];
    }
}

// ---------------- node-sort each window IN PLACE; emit offs + dis ----------------
// One block (256 thr) per 256-node window (~8184 edges). Zero global atomics.
__global__ void k_csr(u32* staging, const int* __restrict__ blkhistB,
                      int* __restrict__ offs, float* __restrict__ dis) {
    __shared__ int cnt[WIN];
    __shared__ int base[WIN];
    int w = blockIdx.x;
    int t = threadIdx.x;
    cnt[t] = 0;
    __syncthreads();
    int start = blkhistB[w * PNB2];
    int end = (w == NDIG - 1) ? N_EDGES : blkhistB[(w + 1) * PNB2];
    u32 buf[MAXE];
    int n = 0;
#pragma unroll
    for (int k = 0; k < MAXE; k++) {
        int i = start + k * 256 + t;
        if (i < end) {
            u32 e = staging[i];
            buf[k] = e;
            n = k + 1;
            atomicAdd(&cnt[e >> 17], 1);  // LDS atomic
        }
    }
    __syncthreads();
    // inclusive scan of cnt -> base
    base[t] = cnt[t];
    __syncthreads();
    for (int off = 1; off < WIN; off <<= 1) {
        int v = base[t];
        int u = (t >= off) ? base[t - off] : 0;
        __syncthreads();
        base[t] = v + u;
        __syncthreads();
    }
    int excl = base[t] - cnt[t];
    base[t] = excl;
    int node = w * WIN + t;
    if (node < N_NODES) {
        offs[node] = start + excl;
        dis[node] = rsqrtf(1.0f + (float)cnt[t]);
    }
    if (w == 0 && t == 0) offs[N_NODES] = N_EDGES;
    __syncthreads();
    cnt[t] = 0;  // reuse as cursor
    __syncthreads();
#pragma unroll
    for (int k = 0; k < MAXE; k++) {
        if (k < n) {
            u32 e = buf[k];
            int cl = (int)(e >> 17);
            int rank = atomicAdd(&cnt[cl], 1);  // LDS atomic
            staging[start + base[cl] + rank] = e;
        }
    }
}

// ---------------- layer 1 GEMM: h1s = (x @ W1) * dis[node]  (bf16) ----------------
__global__ void k_gemm1(const float* __restrict__ x, const float* __restrict__ W1,
                        const float* __restrict__ dis, u16* __restrict__ h1s) {
    __shared__ float Ws[F_IN * HID];  // 8 KB
    for (int t = threadIdx.x; t < F_IN * HID; t += blockDim.x) Ws[t] = W1[t];
    __syncthreads();

    int node = blockIdx.x * blockDim.x + threadIdx.x;
    if (node >= N_NODES) return;

    float acc[HID];
#pragma unroll
    for (int j = 0; j < HID; j++) acc[j] = 0.f;

    const float4* xr = (const float4*)(x + (size_t)node * F_IN);
#pragma unroll 2
    for (int k4 = 0; k4 < F_IN / 4; k4++) {
        float4 v = xr[k4];
        float xv[4] = {v.x, v.y, v.z, v.w};
#pragma unroll
        for (int kk = 0; kk < 4; kk++) {
            const float4* wr = (const float4*)(Ws + (k4 * 4 + kk) * HID);
            float4 w0 = wr[0], w1 = wr[1], w2 = wr[2], w3 = wr[3];
            float xs = xv[kk];
            acc[0]  += xs * w0.x; acc[1]  += xs * w0.y; acc[2]  += xs * w0.z; acc[3]  += xs * w0.w;
            acc[4]  += xs * w1.x; acc[5]  += xs * w1.y; acc[6]  += xs * w1.z; acc[7]  += xs * w1.w;
            acc[8]  += xs * w2.x; acc[9]  += xs * w2.y; acc[10] += xs * w2.z; acc[11] += xs * w2.w;
            acc[12] += xs * w3.x; acc[13] += xs * w3.y; acc[14] += xs * w3.z; acc[15] += xs * w3.w;
        }
    }

    float d = dis[node];
    u32 p[8];
#pragma unroll
    for (int i = 0; i < 8; i++)
        p[i] = (u32)f2bf(acc[2 * i] * d) | ((u32)f2bf(acc[2 * i + 1] * d) << 16);
    u32* dst = (u32*)(h1s + (size_t)node * HID);
#pragma unroll
    for (int i = 0; i < 8; i++) dst[i] = p[i];
}

// ---------------- gather layer 1: 8 lanes/node, uint4 CSR reads ----------------
__global__ void k_gather1(const int* __restrict__ offs, const u32* __restrict__ csr,
                          const float* __restrict__ dis, const u16* __restrict__ h1s,
                          u16* __restrict__ agg1) {
    int t = blockIdx.x * 256 + threadIdx.x;   // exactly N_NODES*8 threads
    int node = t >> 3;
    int f2 = t & 7;
    const u32* hb = (const u32*)h1s;
    u32 v = hb[(size_t)node * 8 + f2];        // self loop (already * dis[node])
    float a0 = bf2f((u16)(v & 0xffff));
    float a1 = bf2f((u16)(v >> 16));
    int s0 = offs[node], s1 = offs[node + 1];
    int j = s0;
    for (; j < s1 && (j & 3); j++) {
        int s = (int)(csr[j] & 0x1FFFFu);
        u32 w = hb[(size_t)s * 8 + f2];
        a0 += bf2f((u16)(w & 0xffff));
        a1 += bf2f((u16)(w >> 16));
    }
    for (; j + 4 <= s1; j += 4) {
        uint4 ss = *(const uint4*)(csr + j);  // broadcast across the node's 8 lanes
        u32 w0 = hb[(size_t)(ss.x & 0x1FFFFu) * 8 + f2];
        u32 w1 = hb[(size_t)(ss.y & 0x1FFFFu) * 8 + f2];
        u32 w2 = hb[(size_t)(ss.z & 0x1FFFFu) * 8 + f2];
        u32 w3 = hb[(size_t)(ss.w & 0x1FFFFu) * 8 + f2];
        a0 += bf2f((u16)(w0 & 0xffff)); a1 += bf2f((u16)(w0 >> 16));
        a0 += bf2f((u16)(w1 & 0xffff)); a1 += bf2f((u16)(w1 >> 16));
        a0 += bf2f((u16)(w2 & 0xffff)); a1 += bf2f((u16)(w2 >> 16));
        a0 += bf2f((u16)(w3 & 0xffff)); a1 += bf2f((u16)(w3 >> 16));
    }
    for (; j < s1; j++) {
        int s = (int)(csr[j] & 0x1FFFFu);
        u32 w = hb[(size_t)s * 8 + f2];
        a0 += bf2f((u16)(w & 0xffff));
        a1 += bf2f((u16)(w >> 16));
    }
    float dc = dis[node];
    ((u32*)agg1)[(size_t)node * 8 + f2] =
        (u32)f2bf(a0 * dc) | ((u32)f2bf(a1 * dc) << 16);
}

// ---------------- layer 2: h = relu(agg1+b1); h2s = (h @ W2) * dis  (bf16, padded to 16) ----------------
__global__ void k_layer2(const u16* __restrict__ agg1, const float* __restrict__ b1,
                         const float* __restrict__ W2, const float* __restrict__ dis,
                         u16* __restrict__ h2s) {
    __shared__ float Ws[HID * C_OUT];
    __shared__ float b1s[HID];
    if (threadIdx.x < HID * C_OUT) Ws[threadIdx.x] = W2[threadIdx.x];
    if (threadIdx.x < HID) b1s[threadIdx.x] = b1[threadIdx.x];
    __syncthreads();

    int node = blockIdx.x * blockDim.x + threadIdx.x;
    if (node >= N_NODES) return;

    const uint4* ar = (const uint4*)(agg1 + (size_t)node * HID);
    uint4 q0 = ar[0], q1 = ar[1];
    u32 qs[8] = {q0.x, q0.y, q0.z, q0.w, q1.x, q1.y, q1.z, q1.w};

    float acc[C_OUT];
#pragma unroll
    for (int k = 0; k < C_OUT; k++) acc[k] = 0.f;

#pragma unroll
    for (int i = 0; i < 8; i++) {
        u32 q = qs[i];
        float v0 = bf2f((u16)(q & 0xffff));
        float v1 = bf2f((u16)(q >> 16));
        int j0 = 2 * i, j1 = 2 * i + 1;
        float h0 = fmaxf(v0 + b1s[j0], 0.f);
        float h1v = fmaxf(v1 + b1s[j1], 0.f);
#pragma unroll
        for (int k = 0; k < C_OUT; k++) acc[k] += h0 * Ws[j0 * C_OUT + k] + h1v * Ws[j1 * C_OUT + k];
    }

    float d = dis[node];
    u32 p[8];
#pragma unroll
    for (int i = 0; i < 5; i++)
        p[i] = (u32)f2bf(acc[2 * i] * d) | ((u32)f2bf(acc[2 * i + 1] * d) << 16);
    p[5] = 0; p[6] = 0; p[7] = 0;  // pad features 10..15
    u32* dst = (u32*)(h2s + (size_t)node * HID);
#pragma unroll
    for (int i = 0; i < 8; i++) dst[i] = p[i];
}

// ---------------- gather layer 2 -> d_out (fp32) ----------------
__global__ void k_gather2(const int* __restrict__ offs, const u32* __restrict__ csr,
                          const float* __restrict__ dis, const u16* __restrict__ h2s,
                          float* __restrict__ agg2) {
    int t = blockIdx.x * 256 + threadIdx.x;
    int node = t >> 3;
    int f2 = t & 7;
    if (f2 >= 5) return;  // features 10..15 are zero padding
    const u32* hb = (const u32*)h2s;
    u32 v = hb[(size_t)node * 8 + f2];
    float a0 = bf2f((u16)(v & 0xffff));
    float a1 = bf2f((u16)(v >> 16));
    int s0 = offs[node], s1 = offs[node + 1];
    int j = s0;
    for (; j < s1 && (j & 3); j++) {
        int s = (int)(csr[j] & 0x1FFFFu);
        u32 w = hb[(size_t)s * 8 + f2];
        a0 += bf2f((u16)(w & 0xffff));
        a1 += bf2f((u16)(w >> 16));
    }
    for (; j + 4 <= s1; j += 4) {
        uint4 ss = *(const uint4*)(csr + j);
        u32 w0 = hb[(size_t)(ss.x & 0x1FFFFu) * 8 + f2];
        u32 w1 = hb[(size_t)(ss.y & 0x1FFFFu) * 8 + f2];
        u32 w2 = hb[(size_t)(ss.z & 0x1FFFFu) * 8 + f2];
        u32 w3 = hb[(size_t)(ss.w & 0x1FFFFu) * 8 + f2];
        a0 += bf2f((u16)(w0 & 0xffff)); a1 += bf2f((u16)(w0 >> 16));
        a0 += bf2f((u16)(w1 & 0xffff)); a1 += bf2f((u16)(w1 >> 16));
        a0 += bf2f((u16)(w2 & 0xffff)); a1 += bf2f((u16)(w2 >> 16));
        a0 += bf2f((u16)(w3 & 0xffff)); a1 += bf2f((u16)(w3 >> 16));
    }
    for (; j < s1; j++) {
        int s = (int)(csr[j] & 0x1FFFFu);
        u32 w = hb[(size_t)s * 8 + f2];
        a0 += bf2f((u16)(w & 0xffff));
        a1 += bf2f((u16)(w >> 16));
    }
    float dc = dis[node];
    float2 o = make_float2(a0 * dc, a1 * dc);
    *(float2*)(agg2 + (size_t)node * C_OUT + 2 * f2) = o;  // 8B-aligned
}

// ---------------- final: log_softmax in place on d_out ----------------
__global__ void k_final(float* __restrict__ agg2, const float* __restrict__ b2) {
    __shared__ float b2s[C_OUT];
    if (threadIdx.x < C_OUT) b2s[threadIdx.x] = b2[threadIdx.x];
    __syncthreads();

    int i = blockIdx.x * blockDim.x + threadIdx.x;
    if (i >= N_NODES) return;

    float* ar = agg2 + (size_t)i * C_OUT;
    float v[C_OUT];
    float m = -1e30f;
#pragma unroll
    for (int k = 0; k < C_OUT; k++) {
        v[k] = ar[k] + b2s[k];
        m = fmaxf(m, v[k]);
    }
    float s = 0.f;
#pragma unroll
    for (int k = 0; k < C_OUT; k++) s += expf(v[k] - m);
    float ls = logf(s) + m;
#pragma unroll
    for (int k = 0; k < C_OUT; k++) ar[k] = v[k] - ls;
}

// ---------------- launch ----------------
extern "C" void kernel_launch(void* const* d_in, const int* in_sizes, int n_in,
                              void* d_out, int out_size, void* d_ws, size_t ws_size,
                              hipStream_t stream) {
    const float* x  = (const float*)d_in[0];
    const int*   ei = (const int*)d_in[1];
    const float* W1 = (const float*)d_in[2];
    const float* b1 = (const float*)d_in[3];
    const float* W2 = (const float*)d_in[4];
    const float* b2 = (const float*)d_in[5];
    float* out = (float*)d_out;

    const int* row = ei;            // sources
    const int* col = ei + N_EDGES;  // targets

    // workspace (~18.4 MB). agg1 (bf16, 3.2MB) lives in d_out, dead before
    // k_gather2 rewrites d_out as fp32.
    char* ws = (char*)d_ws;
    float* dis      = (float*)(ws);                   // 400000 B
    int*   offs     = (int*)(ws + 400000);            // N+1 ints
    int*   blkhistA = (int*)(ws + 800016);            // raw hist, 200192 ints = 800768 B
    int*   blkhistB = (int*)(ws + 1600784);           // scanned, 800768 B
    int*   psum     = (int*)(ws + 2401552);           // 782 ints
    u32*   staging  = (u32*)(ws + 2404688);           // 12.8 MB (16B aligned), becomes CSR
    u16*   h1s      = (u16*)(ws + 15204688);          // 3.2 MB
    u16*   h2s      = (u16*)(ws + 15204688);          // alias (h1s dead after gather1)
    u16*   agg1     = (u16*)d_out;                    // 3.2 MB scratch in d_out
    float* agg2     = out;                            // finalized in place

    const int B = 256;
    int gN  = (N_NODES + B - 1) / B;            // 391
    int gN8 = (N_NODES * 8) / B;                // 3125 exact

    // deterministic window partition + in-window node sort (zero global atomics)
    k_pcnt  <<<PNB2, B, 0, stream>>>(col, blkhistA);
    k_s1    <<<SB1, B, 0, stream>>>(blkhistA, psum);
    k_s2    <<<1, 1024, 0, stream>>>(psum);
    k_s3    <<<SB1, B, 0, stream>>>(blkhistA, psum, blkhistB);
    k_pwrite<<<PNB2, 512, 0, stream>>>(row, col, blkhistA, blkhistB, staging);
    k_csr   <<<NDIG, B, 0, stream>>>(staging, blkhistB, offs, dis);
    // dense pipeline
    k_gemm1 <<<gN, B, 0, stream>>>(x, W1, dis, h1s);
    k_gather1<<<gN8, B, 0, stream>>>(offs, staging, dis, h1s, agg1);
    k_layer2<<<gN, B, 0, stream>>>(agg1, b1, W2, dis, h2s);
    k_gather2<<<gN8, B, 0, stream>>>(offs, staging, dis, h2s, agg2);
    k_final <<<gN, B, 0, stream>>>(agg2, b2);
}

// Round 11
// 243.775 us; speedup vs baseline: 3.0315x; 1.0309x over previous
//
#include <hip/hip_runtime.h>
#include <math.h>

#define N_NODES 100000
#define N_EDGES 3200000
#define F_IN 128
#define HID 16
#define C_OUT 10
#define WIN 256       // nodes per window
#define NDIG 391      // ceil(N_NODES/WIN)
#define PNB2 500      // partition blocks (EPB*PNB2 = N_EDGES exact)
#define EPB 6400      // edges per partition block; 6400*4B = 25600B -> 16B-aligned slices
#define SCN (NDIG * PNB2)   // 195500
#define SB1 764       // ceil(SCN/256)
#define MAXE 40       // per-thread staged entries in k_csr (cap 10240 vs mean 8192, ~22 sigma)

typedef unsigned short u16;
typedef unsigned int u32;

__device__ __forceinline__ float bf2f(u16 u) {
    return __uint_as_float(((u32)u) << 16);
}
__device__ __forceinline__ u16 f2bf(float f) {
    u32 x = __float_as_uint(f);
    u32 r = (x + 0x7fffu + ((x >> 16) & 1u)) >> 16;  // round-nearest-even
    return (u16)r;
}
__device__ __forceinline__ void acc8(float* a, uint4 w) {
    a[0] += bf2f((u16)(w.x & 0xffff)); a[1] += bf2f((u16)(w.x >> 16));
    a[2] += bf2f((u16)(w.y & 0xffff)); a[3] += bf2f((u16)(w.y >> 16));
    a[4] += bf2f((u16)(w.z & 0xffff)); a[5] += bf2f((u16)(w.z >> 16));
    a[6] += bf2f((u16)(w.w & 0xffff)); a[7] += bf2f((u16)(w.w >> 16));
}

// ---------------- partition 1: per-block window histogram, uint4 edge reads ----------------
__global__ void k_pcnt(const int* __restrict__ col, int* __restrict__ blkhistA) {
    __shared__ int h[NDIG];
    for (int i = threadIdx.x; i < NDIG; i += 256) h[i] = 0;
    __syncthreads();
    const uint4* c4 = (const uint4*)(col + blockIdx.x * EPB);
    for (int i = threadIdx.x; i < EPB / 4; i += 256) {
        uint4 c = c4[i];
        atomicAdd(&h[c.x >> 8], 1);
        atomicAdd(&h[c.y >> 8], 1);
        atomicAdd(&h[c.z >> 8], 1);
        atomicAdd(&h[c.w >> 8], 1);
    }
    __syncthreads();
    for (int d = threadIdx.x; d < NDIG; d += 256)
        blkhistA[d * PNB2 + blockIdx.x] = h[d];  // digit-major, raw (kept)
}

// ---------------- partition 2: exclusive scan blkhistA -> blkhistB ----------------
__global__ void k_s1(const int* __restrict__ blkhistA, int* __restrict__ psum) {
    __shared__ int sm[256];
    int i = blockIdx.x * 256 + threadIdx.x;
    sm[threadIdx.x] = (i < SCN) ? blkhistA[i] : 0;
    __syncthreads();
    for (int off = 128; off > 0; off >>= 1) {
        if (threadIdx.x < off) sm[threadIdx.x] += sm[threadIdx.x + off];
        __syncthreads();
    }
    if (threadIdx.x == 0) psum[blockIdx.x] = sm[0];
}

__global__ void k_s2(int* __restrict__ psum) {  // exclusive scan of SB1=764 entries
    const int T = 1024;
    __shared__ int part[T];
    int t = threadIdx.x;
    int v0 = (t < SB1) ? psum[t] : 0;
    part[t] = v0;
    __syncthreads();
    for (int off = 1; off < T; off <<= 1) {
        int v = part[t];
        int u = (t >= off) ? part[t - off] : 0;
        __syncthreads();
        part[t] = v + u;
        __syncthreads();
    }
    if (t < SB1) psum[t] = part[t] - v0;  // exclusive
}

__global__ void k_s3(const int* __restrict__ blkhistA, const int* __restrict__ psum,
                     int* __restrict__ blkhistB) {
    __shared__ int sm[256];
    int i = blockIdx.x * 256 + threadIdx.x;
    int t = threadIdx.x;
    int v = (i < SCN) ? blkhistA[i] : 0;
    sm[t] = v;
    __syncthreads();
    for (int off = 1; off < 256; off <<= 1) {
        int a = sm[t];
        int b = (t >= off) ? sm[t - off] : 0;
        __syncthreads();
        sm[t] = a + b;
        __syncthreads();
    }
    if (i < SCN) blkhistB[i] = psum[blockIdx.x] + sm[t] - v;  // exclusive global offset
}

// ---------------- partition 3: LDS-sorted scatter -> run-coalesced staging writes ----------------
// entry: (c & 255) << 17 | src   (8 + 17 = 25 bits).  512 threads/block.
__global__ void __launch_bounds__(512) k_pwrite(
        const int* __restrict__ row, const int* __restrict__ col,
        const int* __restrict__ blkhistA, const int* __restrict__ blkhistB,
        u32* __restrict__ staging) {
    __shared__ u32 sorted[EPB];     // 25600 B
    __shared__ u16 dwin[EPB];       // 12800 B
    __shared__ int gbase[NDIG];
    __shared__ int lbase[NDIG];
    __shared__ int lcur[NDIG];
    __shared__ int scan[512];

    int t = threadIdx.x;
    int b = blockIdx.x;
    int hv = 0;
    if (t < NDIG) {
        hv = blkhistA[t * PNB2 + b];
        gbase[t] = blkhistB[t * PNB2 + b];
        lcur[t] = 0;
    }
    scan[t] = hv;
    __syncthreads();
    for (int off = 1; off < 512; off <<= 1) {
        int v = scan[t];
        int u = (t >= off) ? scan[t - off] : 0;
        __syncthreads();
        scan[t] = v + u;
        __syncthreads();
    }
    if (t < NDIG) lbase[t] = scan[t] - hv;  // exclusive local offset
    __syncthreads();

    const uint4* c4 = (const uint4*)(col + b * EPB);
    const uint4* r4 = (const uint4*)(row + b * EPB);
    for (int i = t; i < EPB / 4; i += 512) {
        uint4 c = c4[i];
        uint4 r = r4[i];
        int d, rank, pos;
        d = (int)(c.x >> 8); rank = atomicAdd(&lcur[d], 1); pos = lbase[d] + rank;
        sorted[pos] = ((c.x & 255u) << 17) | r.x; dwin[pos] = (u16)d;
        d = (int)(c.y >> 8); rank = atomicAdd(&lcur[d], 1); pos = lbase[d] + rank;
        sorted[pos] = ((c.y & 255u) << 17) | r.y; dwin[pos] = (u16)d;
        d = (int)(c.z >> 8); rank = atomicAdd(&lcur[d], 1); pos = lbase[d] + rank;
        sorted[pos] = ((c.z & 255u) << 17) | r.z; dwin[pos] = (u16)d;
        d = (int)(c.w >> 8); rank = atomicAdd(&lcur[d], 1); pos = lbase[d] + rank;
        sorted[pos] = ((c.w & 255u) << 17) | r.w; dwin[pos] = (u16)d;
    }
    __syncthreads();

    // copy out: consecutive i -> consecutive dest within each window run
    for (int i = t; i < EPB; i += 512) {
        int d = dwin[i];
        staging[gbase[d] + (i - lbase[d])] = sorted[i];
    }
}

// ---------------- node-sort each window IN PLACE; emit offs + dis ----------------
__global__ void k_csr(u32* staging, const int* __restrict__ blkhistB,
                      int* __restrict__ offs, float* __restrict__ dis) {
    __shared__ int cnt[WIN];
    __shared__ int base[WIN];
    int w = blockIdx.x;
    int t = threadIdx.x;
    cnt[t] = 0;
    __syncthreads();
    int start = blkhistB[w * PNB2];
    int end = (w == NDIG - 1) ? N_EDGES : blkhistB[(w + 1) * PNB2];
    u32 buf[MAXE];
    int n = 0;
#pragma unroll
    for (int k = 0; k < MAXE; k++) {
        int i = start + k * 256 + t;
        if (i < end) {
            u32 e = staging[i];
            buf[k] = e;
            n = k + 1;
            atomicAdd(&cnt[e >> 17], 1);  // LDS atomic
        }
    }
    __syncthreads();
    base[t] = cnt[t];
    __syncthreads();
    for (int off = 1; off < WIN; off <<= 1) {
        int v = base[t];
        int u = (t >= off) ? base[t - off] : 0;
        __syncthreads();
        base[t] = v + u;
        __syncthreads();
    }
    int excl = base[t] - cnt[t];
    base[t] = excl;
    int node = w * WIN + t;
    if (node < N_NODES) {
        offs[node] = start + excl;
        dis[node] = rsqrtf(1.0f + (float)cnt[t]);
    }
    if (w == 0 && t == 0) offs[N_NODES] = N_EDGES;
    __syncthreads();
    cnt[t] = 0;  // reuse as cursor
    __syncthreads();
#pragma unroll
    for (int k = 0; k < MAXE; k++) {
        if (k < n) {
            u32 e = buf[k];
            int cl = (int)(e >> 17);
            int rank = atomicAdd(&cnt[cl], 1);  // LDS atomic
            staging[start + base[cl] + rank] = e;
        }
    }
}

// ---------------- layer 1 GEMM: h1s = (x @ W1) * dis[node]  (bf16) ----------------
__global__ void k_gemm1(const float* __restrict__ x, const float* __restrict__ W1,
                        const float* __restrict__ dis, u16* __restrict__ h1s) {
    __shared__ float Ws[F_IN * HID];  // 8 KB
    for (int t = threadIdx.x; t < F_IN * HID; t += blockDim.x) Ws[t] = W1[t];
    __syncthreads();

    int node = blockIdx.x * blockDim.x + threadIdx.x;
    if (node >= N_NODES) return;

    float acc[HID];
#pragma unroll
    for (int j = 0; j < HID; j++) acc[j] = 0.f;

    const float4* xr = (const float4*)(x + (size_t)node * F_IN);
#pragma unroll 2
    for (int k4 = 0; k4 < F_IN / 4; k4++) {
        float4 v = xr[k4];
        float xv[4] = {v.x, v.y, v.z, v.w};
#pragma unroll
        for (int kk = 0; kk < 4; kk++) {
            const float4* wr = (const float4*)(Ws + (k4 * 4 + kk) * HID);
            float4 w0 = wr[0], w1 = wr[1], w2 = wr[2], w3 = wr[3];
            float xs = xv[kk];
            acc[0]  += xs * w0.x; acc[1]  += xs * w0.y; acc[2]  += xs * w0.z; acc[3]  += xs * w0.w;
            acc[4]  += xs * w1.x; acc[5]  += xs * w1.y; acc[6]  += xs * w1.z; acc[7]  += xs * w1.w;
            acc[8]  += xs * w2.x; acc[9]  += xs * w2.y; acc[10] += xs * w2.z; acc[11] += xs * w2.w;
            acc[12] += xs * w3.x; acc[13] += xs * w3.y; acc[14] += xs * w3.z; acc[15] += xs * w3.w;
        }
    }

    float d = dis[node];
    u32 p[8];
#pragma unroll
    for (int i = 0; i < 8; i++)
        p[i] = (u32)f2bf(acc[2 * i] * d) | ((u32)f2bf(acc[2 * i + 1] * d) << 16);
    u32* dst = (u32*)(h1s + (size_t)node * HID);
#pragma unroll
    for (int i = 0; i < 8; i++) dst[i] = p[i];
}

// ---------------- gather layer 1: 2 lanes/node, uint4 h-row loads ----------------
__global__ void k_gather1(const int* __restrict__ offs, const u32* __restrict__ csr,
                          const float* __restrict__ dis, const u16* __restrict__ h1s,
                          u16* __restrict__ agg1) {
    int t = blockIdx.x * 256 + threadIdx.x;
    if (t >= N_NODES * 2) return;
    int node = t >> 1;
    int half = t & 1;
    const uint4* hb = (const uint4*)h1s;  // 2 uint4 per 32B row
    float a[8] = {0.f, 0.f, 0.f, 0.f, 0.f, 0.f, 0.f, 0.f};
    acc8(a, hb[(size_t)node * 2 + half]);  // self loop (already * dis[node])
    int s0 = offs[node], s1 = offs[node + 1];
    int j = s0;
    for (; j < s1 && (j & 3); j++)
        acc8(a, hb[(size_t)(csr[j] & 0x1FFFFu) * 2 + half]);
    for (; j + 4 <= s1; j += 4) {
        uint4 ss = *(const uint4*)(csr + j);  // broadcast across the node's 2 lanes
        uint4 w0 = hb[(size_t)(ss.x & 0x1FFFFu) * 2 + half];
        uint4 w1 = hb[(size_t)(ss.y & 0x1FFFFu) * 2 + half];
        uint4 w2 = hb[(size_t)(ss.z & 0x1FFFFu) * 2 + half];
        uint4 w3 = hb[(size_t)(ss.w & 0x1FFFFu) * 2 + half];
        acc8(a, w0); acc8(a, w1); acc8(a, w2); acc8(a, w3);
    }
    for (; j < s1; j++)
        acc8(a, hb[(size_t)(csr[j] & 0x1FFFFu) * 2 + half]);
    float dc = dis[node];
    uint4 o;
    o.x = (u32)f2bf(a[0] * dc) | ((u32)f2bf(a[1] * dc) << 16);
    o.y = (u32)f2bf(a[2] * dc) | ((u32)f2bf(a[3] * dc) << 16);
    o.z = (u32)f2bf(a[4] * dc) | ((u32)f2bf(a[5] * dc) << 16);
    o.w = (u32)f2bf(a[6] * dc) | ((u32)f2bf(a[7] * dc) << 16);
    ((uint4*)agg1)[(size_t)node * 2 + half] = o;
}

// ---------------- layer 2: h = relu(agg1+b1); h2s = (h @ W2) * dis  (bf16, padded to 16) ----------------
__global__ void k_layer2(const u16* __restrict__ agg1, const float* __restrict__ b1,
                         const float* __restrict__ W2, const float* __restrict__ dis,
                         u16* __restrict__ h2s) {
    __shared__ float Ws[HID * C_OUT];
    __shared__ float b1s[HID];
    if (threadIdx.x < HID * C_OUT) Ws[threadIdx.x] = W2[threadIdx.x];
    if (threadIdx.x < HID) b1s[threadIdx.x] = b1[threadIdx.x];
    __syncthreads();

    int node = blockIdx.x * blockDim.x + threadIdx.x;
    if (node >= N_NODES) return;

    const uint4* ar = (const uint4*)(agg1 + (size_t)node * HID);
    uint4 q0 = ar[0], q1 = ar[1];
    u32 qs[8] = {q0.x, q0.y, q0.z, q0.w, q1.x, q1.y, q1.z, q1.w};

    float acc[C_OUT];
#pragma unroll
    for (int k = 0; k < C_OUT; k++) acc[k] = 0.f;

#pragma unroll
    for (int i = 0; i < 8; i++) {
        u32 q = qs[i];
        float v0 = bf2f((u16)(q & 0xffff));
        float v1 = bf2f((u16)(q >> 16));
        int j0 = 2 * i, j1 = 2 * i + 1;
        float h0 = fmaxf(v0 + b1s[j0], 0.f);
        float h1v = fmaxf(v1 + b1s[j1], 0.f);
#pragma unroll
        for (int k = 0; k < C_OUT; k++) acc[k] += h0 * Ws[j0 * C_OUT + k] + h1v * Ws[j1 * C_OUT + k];
    }

    float d = dis[node];
    u32 p[8];
#pragma unroll
    for (int i = 0; i < 5; i++)
        p[i] = (u32)f2bf(acc[2 * i] * d) | ((u32)f2bf(acc[2 * i + 1] * d) << 16);
    p[5] = 0; p[6] = 0; p[7] = 0;  // pad features 10..15
    u32* dst = (u32*)(h2s + (size_t)node * HID);
#pragma unroll
    for (int i = 0; i < 8; i++) dst[i] = p[i];
}

// ---------------- gather layer 2 + fused log_softmax -> d_out (fp32) ----------------
__global__ void k_gather2(const int* __restrict__ offs, const u32* __restrict__ csr,
                          const float* __restrict__ dis, const u16* __restrict__ h2s,
                          const float* __restrict__ b2, float* __restrict__ out) {
    __shared__ float b2s[C_OUT];
    if (threadIdx.x < C_OUT) b2s[threadIdx.x] = b2[threadIdx.x];
    __syncthreads();

    int t = blockIdx.x * 256 + threadIdx.x;
    if (t >= N_NODES * 2) return;
    int node = t >> 1;
    int half = t & 1;  // half0: feats 0-7, half1: feats 8,9 (+6 zero pads)
    const uint4* hb = (const uint4*)h2s;
    float a[8] = {0.f, 0.f, 0.f, 0.f, 0.f, 0.f, 0.f, 0.f};
    acc8(a, hb[(size_t)node * 2 + half]);  // self loop
    int s0 = offs[node], s1 = offs[node + 1];
    int j = s0;
    for (; j < s1 && (j & 3); j++)
        acc8(a, hb[(size_t)(csr[j] & 0x1FFFFu) * 2 + half]);
    for (; j + 4 <= s1; j += 4) {
        uint4 ss = *(const uint4*)(csr + j);
        uint4 w0 = hb[(size_t)(ss.x & 0x1FFFFu) * 2 + half];
        uint4 w1 = hb[(size_t)(ss.y & 0x1FFFFu) * 2 + half];
        uint4 w2 = hb[(size_t)(ss.z & 0x1FFFFu) * 2 + half];
        uint4 w3 = hb[(size_t)(ss.w & 0x1FFFFu) * 2 + half];
        acc8(a, w0); acc8(a, w1); acc8(a, w2); acc8(a, w3);
    }
    for (; j < s1; j++)
        acc8(a, hb[(size_t)(csr[j] & 0x1FFFFu) * 2 + half]);

    float dc = dis[node];
    int nf = half ? 2 : 8;  // valid logits this lane
    float lg[8];
    float m = -1e30f;
#pragma unroll
    for (int k = 0; k < 8; k++) {
        lg[k] = a[k] * dc + b2s[(half * 8 + k) % C_OUT];  // pads unused below
        if (k < nf) m = fmaxf(m, lg[k]);
    }
    m = fmaxf(m, __shfl_xor(m, 1));          // pair max over 10 logits
    float s = 0.f;
#pragma unroll
    for (int k = 0; k < 8; k++)
        if (k < nf) s += expf(lg[k] - m);
    s += __shfl_xor(s, 1);                   // pair sum
    float ls = logf(s) + m;
    float* dst = out + (size_t)node * C_OUT + half * 8;
    if (half == 0) {
#pragma unroll
        for (int i = 0; i < 4; i++)
            *(float2*)(dst + 2 * i) = make_float2(lg[2 * i] - ls, lg[2 * i + 1] - ls);
    } else {
        *(float2*)dst = make_float2(lg[0] - ls, lg[1] - ls);
    }
}

// ---------------- launch ----------------
extern "C" void kernel_launch(void* const* d_in, const int* in_sizes, int n_in,
                              void* d_out, int out_size, void* d_ws, size_t ws_size,
                              hipStream_t stream) {
    const float* x  = (const float*)d_in[0];
    const int*   ei = (const int*)d_in[1];
    const float* W1 = (const float*)d_in[2];
    const float* b1 = (const float*)d_in[3];
    const float* W2 = (const float*)d_in[4];
    const float* b2 = (const float*)d_in[5];
    float* out = (float*)d_out;

    const int* row = ei;            // sources
    const int* col = ei + N_EDGES;  // targets

    // workspace (~18.4 MB). agg1 (bf16, 3.2MB) lives in d_out, dead before
    // k_gather2 rewrites d_out as fp32.
    char* ws = (char*)d_ws;
    float* dis      = (float*)(ws);                   // 400000 B
    int*   offs     = (int*)(ws + 400000);            // N+1 ints
    int*   blkhistA = (int*)(ws + 800016);            // raw hist, padded to 764*256 ints
    int*   blkhistB = (int*)(ws + 1582352);           // scanned
    int*   psum     = (int*)(ws + 2364688);           // 764 ints
    u32*   staging  = (u32*)(ws + 2367744);           // 12.8 MB (16B aligned), becomes CSR
    u16*   h1s      = (u16*)(ws + 15167744);          // 3.2 MB (16B aligned)
    u16*   h2s      = (u16*)(ws + 15167744);          // alias (h1s dead after gather1)
    u16*   agg1     = (u16*)d_out;                    // 3.2 MB scratch in d_out
    float* agg2     = out;

    const int B = 256;
    int gN  = (N_NODES + B - 1) / B;            // 391
    int gN2 = (N_NODES * 2 + B - 1) / B;        // 782

    // deterministic window partition + in-window node sort (zero global atomics)
    k_pcnt  <<<PNB2, B, 0, stream>>>(col, blkhistA);
    k_s1    <<<SB1, B, 0, stream>>>(blkhistA, psum);
    k_s2    <<<1, 1024, 0, stream>>>(psum);
    k_s3    <<<SB1, B, 0, stream>>>(blkhistA, psum, blkhistB);
    k_pwrite<<<PNB2, 512, 0, stream>>>(row, col, blkhistA, blkhistB, staging);
    k_csr   <<<NDIG, B, 0, stream>>>(staging, blkhistB, offs, dis);
    // dense pipeline
    k_gemm1 <<<gN, B, 0, stream>>>(x, W1, dis, h1s);
    k_gather1<<<gN2, B, 0, stream>>>(offs, staging, dis, h1s, agg1);
    k_layer2<<<gN, B, 0, stream>>>(agg1, b1, W2, dis, h2s);
    k_gather2<<<gN2, B, 0, stream>>>(offs, staging, dis, h2s, b2, agg2);
    (void)agg2;
}

// Round 12
// 237.306 us; speedup vs baseline: 3.1141x; 1.0273x over previous
//
#include <hip/hip_runtime.h>
#include <math.h>

#define N_NODES 100000
#define N_EDGES 3200000
#define F_IN 128
#define HID 16
#define C_OUT 10
#define WIN 256       // nodes per window
#define NDIG 391      // ceil(N_NODES/WIN)
#define PNB2 500      // partition blocks (EPB*PNB2 = N_EDGES exact)
#define EPB 6400      // edges per partition block; 16B-aligned slices
#define SCN (NDIG * PNB2)   // 195500
#define SB1 764       // ceil(SCN/256)
#define MAXE 40       // per-thread staged entries in k_csr (cap 10240 vs mean 8192)

typedef unsigned short u16;
typedef unsigned int u32;

__device__ __forceinline__ float bf2f(u16 u) {
    return __uint_as_float(((u32)u) << 16);
}
__device__ __forceinline__ u16 f2bf(float f) {
    u32 x = __float_as_uint(f);
    u32 r = (x + 0x7fffu + ((x >> 16) & 1u)) >> 16;  // round-nearest-even
    return (u16)r;
}
__device__ __forceinline__ void acc8(float* a, uint4 w) {
    a[0] += bf2f((u16)(w.x & 0xffff)); a[1] += bf2f((u16)(w.x >> 16));
    a[2] += bf2f((u16)(w.y & 0xffff)); a[3] += bf2f((u16)(w.y >> 16));
    a[4] += bf2f((u16)(w.z & 0xffff)); a[5] += bf2f((u16)(w.z >> 16));
    a[6] += bf2f((u16)(w.w & 0xffff)); a[7] += bf2f((u16)(w.w >> 16));
}

// ---------------- partition 1: per-block window histogram, uint4 edge reads ----------------
__global__ void k_pcnt(const int* __restrict__ col, int* __restrict__ blkhistA) {
    __shared__ int h[NDIG];
    for (int i = threadIdx.x; i < NDIG; i += 256) h[i] = 0;
    __syncthreads();
    const uint4* c4 = (const uint4*)(col + blockIdx.x * EPB);
    for (int i = threadIdx.x; i < EPB / 4; i += 256) {
        uint4 c = c4[i];
        atomicAdd(&h[c.x >> 8], 1);
        atomicAdd(&h[c.y >> 8], 1);
        atomicAdd(&h[c.z >> 8], 1);
        atomicAdd(&h[c.w >> 8], 1);
    }
    __syncthreads();
    for (int d = threadIdx.x; d < NDIG; d += 256)
        blkhistA[d * PNB2 + blockIdx.x] = h[d];  // digit-major, raw (kept)
}

// ---------------- partition 2a: per-256-chunk sums ----------------
__global__ void k_s1(const int* __restrict__ blkhistA, int* __restrict__ psum) {
    __shared__ int sm[256];
    int i = blockIdx.x * 256 + threadIdx.x;
    sm[threadIdx.x] = (i < SCN) ? blkhistA[i] : 0;
    __syncthreads();
    for (int off = 128; off > 0; off >>= 1) {
        if (threadIdx.x < off) sm[threadIdx.x] += sm[threadIdx.x + off];
        __syncthreads();
    }
    if (threadIdx.x == 0) psum[blockIdx.x] = sm[0];
}

// ---------------- partition 2b: chunk scan (redundant per block) + local scan -> blkhistB ----------------
__global__ void k_s3(const int* __restrict__ blkhistA, const int* __restrict__ psum,
                     int* __restrict__ blkhistB) {
    __shared__ int ps[1024];
    __shared__ int sm[256];
    int t = threadIdx.x;
    for (int i = t; i < 1024; i += 256) ps[i] = (i < SB1) ? psum[i] : 0;
    __syncthreads();
    // inclusive Hillis-Steele over 1024 entries, 4 per thread
    for (int off = 1; off < 1024; off <<= 1) {
        int v[4];
#pragma unroll
        for (int j = 0; j < 4; j++) {
            int idx = t + j * 256;
            v[j] = ps[idx] + ((idx >= off) ? ps[idx - off] : 0);
        }
        __syncthreads();
#pragma unroll
        for (int j = 0; j < 4; j++) ps[t + j * 256] = v[j];
        __syncthreads();
    }
    int bpre = (blockIdx.x > 0) ? ps[blockIdx.x - 1] : 0;  // exclusive chunk prefix

    int i = blockIdx.x * 256 + t;
    int v = (i < SCN) ? blkhistA[i] : 0;
    sm[t] = v;
    __syncthreads();
    for (int off = 1; off < 256; off <<= 1) {
        int a = sm[t];
        int b = (t >= off) ? sm[t - off] : 0;
        __syncthreads();
        sm[t] = a + b;
        __syncthreads();
    }
    if (i < SCN) blkhistB[i] = bpre + sm[t] - v;  // exclusive global offset
}

// ---------------- partition 3: LDS-sorted scatter -> run-coalesced staging writes ----------------
// entry: (c & 255) << 17 | src   (8 + 17 = 25 bits).  512 threads/block.
__global__ void __launch_bounds__(512) k_pwrite(
        const int* __restrict__ row, const int* __restrict__ col,
        const int* __restrict__ blkhistA, const int* __restrict__ blkhistB,
        u32* __restrict__ staging) {
    __shared__ u32 sorted[EPB];     // 25600 B
    __shared__ u16 dwin[EPB];       // 12800 B
    __shared__ int gbase[NDIG];
    __shared__ int lbase[NDIG];
    __shared__ int lcur[NDIG];
    __shared__ int scan[512];

    int t = threadIdx.x;
    int b = blockIdx.x;
    int hv = 0;
    if (t < NDIG) {
        hv = blkhistA[t * PNB2 + b];
        gbase[t] = blkhistB[t * PNB2 + b];
        lcur[t] = 0;
    }
    scan[t] = hv;
    __syncthreads();
    for (int off = 1; off < 512; off <<= 1) {
        int v = scan[t];
        int u = (t >= off) ? scan[t - off] : 0;
        __syncthreads();
        scan[t] = v + u;
        __syncthreads();
    }
    if (t < NDIG) lbase[t] = scan[t] - hv;  // exclusive local offset
    __syncthreads();

    const uint4* c4 = (const uint4*)(col + b * EPB);
    const uint4* r4 = (const uint4*)(row + b * EPB);
    for (int i = t; i < EPB / 4; i += 512) {
        uint4 c = c4[i];
        uint4 r = r4[i];
        int d, rank, pos;
        d = (int)(c.x >> 8); rank = atomicAdd(&lcur[d], 1); pos = lbase[d] + rank;
        sorted[pos] = ((c.x & 255u) << 17) | r.x; dwin[pos] = (u16)d;
        d = (int)(c.y >> 8); rank = atomicAdd(&lcur[d], 1); pos = lbase[d] + rank;
        sorted[pos] = ((c.y & 255u) << 17) | r.y; dwin[pos] = (u16)d;
        d = (int)(c.z >> 8); rank = atomicAdd(&lcur[d], 1); pos = lbase[d] + rank;
        sorted[pos] = ((c.z & 255u) << 17) | r.z; dwin[pos] = (u16)d;
        d = (int)(c.w >> 8); rank = atomicAdd(&lcur[d], 1); pos = lbase[d] + rank;
        sorted[pos] = ((c.w & 255u) << 17) | r.w; dwin[pos] = (u16)d;
    }
    __syncthreads();

    for (int i = t; i < EPB; i += 512) {
        int d = dwin[i];
        staging[gbase[d] + (i - lbase[d])] = sorted[i];
    }
}

// ---------------- node-sort each window IN PLACE; emit offs + dis ----------------
__global__ void k_csr(u32* staging, const int* __restrict__ blkhistB,
                      int* __restrict__ offs, float* __restrict__ dis) {
    __shared__ int cnt[WIN];
    __shared__ int base[WIN];
    int w = blockIdx.x;
    int t = threadIdx.x;
    cnt[t] = 0;
    __syncthreads();
    int start = blkhistB[w * PNB2];
    int end = (w == NDIG - 1) ? N_EDGES : blkhistB[(w + 1) * PNB2];
    u32 buf[MAXE];
    int n = 0;
#pragma unroll
    for (int k = 0; k < MAXE; k++) {
        int i = start + k * 256 + t;
        if (i < end) {
            u32 e = staging[i];
            buf[k] = e;
            n = k + 1;
            atomicAdd(&cnt[e >> 17], 1);  // LDS atomic
        }
    }
    __syncthreads();
    base[t] = cnt[t];
    __syncthreads();
    for (int off = 1; off < WIN; off <<= 1) {
        int v = base[t];
        int u = (t >= off) ? base[t - off] : 0;
        __syncthreads();
        base[t] = v + u;
        __syncthreads();
    }
    int excl = base[t] - cnt[t];
    base[t] = excl;
    int node = w * WIN + t;
    if (node < N_NODES) {
        offs[node] = start + excl;
        dis[node] = rsqrtf(1.0f + (float)cnt[t]);
    }
    if (w == 0 && t == 0) offs[N_NODES] = N_EDGES;
    __syncthreads();
    cnt[t] = 0;  // reuse as cursor
    __syncthreads();
#pragma unroll
    for (int k = 0; k < MAXE; k++) {
        if (k < n) {
            u32 e = buf[k];
            int cl = (int)(e >> 17);
            int rank = atomicAdd(&cnt[cl], 1);  // LDS atomic
            staging[start + base[cl] + rank] = e;
        }
    }
}

// ---------------- layer 1 GEMM: h1s = (x @ W1) * dis[node]  (bf16) ----------------
__global__ void k_gemm1(const float* __restrict__ x, const float* __restrict__ W1,
                        const float* __restrict__ dis, u16* __restrict__ h1s) {
    __shared__ float Ws[F_IN * HID];  // 8 KB
    for (int t = threadIdx.x; t < F_IN * HID; t += blockDim.x) Ws[t] = W1[t];
    __syncthreads();

    int node = blockIdx.x * blockDim.x + threadIdx.x;
    if (node >= N_NODES) return;

    float acc[HID];
#pragma unroll
    for (int j = 0; j < HID; j++) acc[j] = 0.f;

    const float4* xr = (const float4*)(x + (size_t)node * F_IN);
#pragma unroll 2
    for (int k4 = 0; k4 < F_IN / 4; k4++) {
        float4 v = xr[k4];
        float xv[4] = {v.x, v.y, v.z, v.w};
#pragma unroll
        for (int kk = 0; kk < 4; kk++) {
            const float4* wr = (const float4*)(Ws + (k4 * 4 + kk) * HID);
            float4 w0 = wr[0], w1 = wr[1], w2 = wr[2], w3 = wr[3];
            float xs = xv[kk];
            acc[0]  += xs * w0.x; acc[1]  += xs * w0.y; acc[2]  += xs * w0.z; acc[3]  += xs * w0.w;
            acc[4]  += xs * w1.x; acc[5]  += xs * w1.y; acc[6]  += xs * w1.z; acc[7]  += xs * w1.w;
            acc[8]  += xs * w2.x; acc[9]  += xs * w2.y; acc[10] += xs * w2.z; acc[11] += xs * w2.w;
            acc[12] += xs * w3.x; acc[13] += xs * w3.y; acc[14] += xs * w3.z; acc[15] += xs * w3.w;
        }
    }

    float d = dis[node];
    u32 p[8];
#pragma unroll
    for (int i = 0; i < 8; i++)
        p[i] = (u32)f2bf(acc[2 * i] * d) | ((u32)f2bf(acc[2 * i + 1] * d) << 16);
    u32* dst = (u32*)(h1s + (size_t)node * HID);
#pragma unroll
    for (int i = 0; i < 8; i++) dst[i] = p[i];
}

// ---------------- gather1 + layer2 fused: agg1 in registers -> relu -> @W2 -> h2s ----------------
// 2 lanes/node; lane pair exchanges agg1 halves via shfl (agg1 never hits memory).
__global__ void k_gl1(const int* __restrict__ offs, const u32* __restrict__ csr,
                      const float* __restrict__ dis, const u16* __restrict__ h1s,
                      const float* __restrict__ b1, const float* __restrict__ W2,
                      u16* __restrict__ h2s) {
    __shared__ float Ws[HID * C_OUT];
    __shared__ float b1s[HID];
    if (threadIdx.x < HID * C_OUT) Ws[threadIdx.x] = W2[threadIdx.x];
    if (threadIdx.x < HID) b1s[threadIdx.x] = b1[threadIdx.x];
    __syncthreads();

    int t = blockIdx.x * 256 + threadIdx.x;
    if (t >= N_NODES * 2) return;
    int node = t >> 1;
    int half = t & 1;
    const uint4* hb = (const uint4*)h1s;
    float a[8] = {0.f, 0.f, 0.f, 0.f, 0.f, 0.f, 0.f, 0.f};
    acc8(a, hb[(size_t)node * 2 + half]);  // self loop (pre-scaled)
    int o = offs[node + half];             // pair loads offs[node], offs[node+1]
    int oo = __shfl_xor(o, 1);
    int s0 = half ? oo : o;
    int s1 = half ? o : oo;
    int j = s0;
    for (; j < s1 && (j & 3); j++)
        acc8(a, hb[(size_t)(csr[j] & 0x1FFFFu) * 2 + half]);
    for (; j + 4 <= s1; j += 4) {
        uint4 ss = *(const uint4*)(csr + j);
        uint4 w0 = hb[(size_t)(ss.x & 0x1FFFFu) * 2 + half];
        uint4 w1 = hb[(size_t)(ss.y & 0x1FFFFu) * 2 + half];
        uint4 w2 = hb[(size_t)(ss.z & 0x1FFFFu) * 2 + half];
        uint4 w3 = hb[(size_t)(ss.w & 0x1FFFFu) * 2 + half];
        acc8(a, w0); acc8(a, w1); acc8(a, w2); acc8(a, w3);
    }
    for (; j < s1; j++)
        acc8(a, hb[(size_t)(csr[j] & 0x1FFFFu) * 2 + half]);

    float dc = dis[node];
    float own[8], oth[8];
#pragma unroll
    for (int k = 0; k < 8; k++) own[k] = a[k] * dc;      // agg1 feats half*8+k (fp32)
#pragma unroll
    for (int k = 0; k < 8; k++) oth[k] = __shfl_xor(own[k], 1);
    float h[16];
#pragma unroll
    for (int k = 0; k < 8; k++) {
        h[k]     = half ? oth[k] : own[k];
        h[8 + k] = half ? own[k] : oth[k];
    }
#pragma unroll
    for (int jj = 0; jj < 16; jj++) h[jj] = fmaxf(h[jj] + b1s[jj], 0.f);

    int nf = half ? 2 : 8;
    float outv[8];
#pragma unroll
    for (int k = 0; k < 8; k++) {
        float s = 0.f;
        if (k < nf) {
            int kk = half * 8 + k;
#pragma unroll
            for (int jj = 0; jj < 16; jj++) s += h[jj] * Ws[jj * C_OUT + kk];
        }
        outv[k] = s * dc;  // pre-scale for gather2
    }
    uint4 ov;
    ov.x = (u32)f2bf(outv[0]) | ((u32)f2bf(outv[1]) << 16);
    ov.y = half ? 0u : ((u32)f2bf(outv[2]) | ((u32)f2bf(outv[3]) << 16));
    ov.z = half ? 0u : ((u32)f2bf(outv[4]) | ((u32)f2bf(outv[5]) << 16));
    ov.w = half ? 0u : ((u32)f2bf(outv[6]) | ((u32)f2bf(outv[7]) << 16));
    ((uint4*)h2s)[(size_t)node * 2 + half] = ov;
}

// ---------------- gather layer 2 + fused log_softmax -> d_out (fp32) ----------------
__global__ void k_gather2(const int* __restrict__ offs, const u32* __restrict__ csr,
                          const float* __restrict__ dis, const u16* __restrict__ h2s,
                          const float* __restrict__ b2, float* __restrict__ out) {
    __shared__ float b2s[C_OUT];
    if (threadIdx.x < C_OUT) b2s[threadIdx.x] = b2[threadIdx.x];
    __syncthreads();

    int t = blockIdx.x * 256 + threadIdx.x;
    if (t >= N_NODES * 2) return;
    int node = t >> 1;
    int half = t & 1;  // half0: feats 0-7, half1: feats 8,9 (+6 zero pads)
    const uint4* hb = (const uint4*)h2s;
    float a[8] = {0.f, 0.f, 0.f, 0.f, 0.f, 0.f, 0.f, 0.f};
    acc8(a, hb[(size_t)node * 2 + half]);  // self loop
    int o = offs[node + half];
    int oo = __shfl_xor(o, 1);
    int s0 = half ? oo : o;
    int s1 = half ? o : oo;
    int j = s0;
    for (; j < s1 && (j & 3); j++)
        acc8(a, hb[(size_t)(csr[j] & 0x1FFFFu) * 2 + half]);
    for (; j + 4 <= s1; j += 4) {
        uint4 ss = *(const uint4*)(csr + j);
        uint4 w0 = hb[(size_t)(ss.x & 0x1FFFFu) * 2 + half];
        uint4 w1 = hb[(size_t)(ss.y & 0x1FFFFu) * 2 + half];
        uint4 w2 = hb[(size_t)(ss.z & 0x1FFFFu) * 2 + half];
        uint4 w3 = hb[(size_t)(ss.w & 0x1FFFFu) * 2 + half];
        acc8(a, w0); acc8(a, w1); acc8(a, w2); acc8(a, w3);
    }
    for (; j < s1; j++)
        acc8(a, hb[(size_t)(csr[j] & 0x1FFFFu) * 2 + half]);

    float dc = dis[node];
    int nf = half ? 2 : 8;
    float lg[8];
    float m = -1e30f;
#pragma unroll
    for (int k = 0; k < 8; k++) {
        lg[k] = a[k] * dc + b2s[(half * 8 + k) % C_OUT];
        if (k < nf) m = fmaxf(m, lg[k]);
    }
    m = fmaxf(m, __shfl_xor(m, 1));          // pair max over 10 logits
    float s = 0.f;
#pragma unroll
    for (int k = 0; k < 8; k++)
        if (k < nf) s += expf(lg[k] - m);
    s += __shfl_xor(s, 1);                   // pair sum
    float ls = logf(s) + m;
    float* dst = out + (size_t)node * C_OUT + half * 8;
    if (half == 0) {
#pragma unroll
        for (int i = 0; i < 4; i++)
            *(float2*)(dst + 2 * i) = make_float2(lg[2 * i] - ls, lg[2 * i + 1] - ls);
    } else {
        *(float2*)dst = make_float2(lg[0] - ls, lg[1] - ls);
    }
}

// ---------------- launch ----------------
extern "C" void kernel_launch(void* const* d_in, const int* in_sizes, int n_in,
                              void* d_out, int out_size, void* d_ws, size_t ws_size,
                              hipStream_t stream) {
    const float* x  = (const float*)d_in[0];
    const int*   ei = (const int*)d_in[1];
    const float* W1 = (const float*)d_in[2];
    const float* b1 = (const float*)d_in[3];
    const float* W2 = (const float*)d_in[4];
    const float* b2 = (const float*)d_in[5];
    float* out = (float*)d_out;

    const int* row = ei;            // sources
    const int* col = ei + N_EDGES;  // targets

    char* ws = (char*)d_ws;
    float* dis      = (float*)(ws);                   // 400000 B
    int*   offs     = (int*)(ws + 400000);            // N+1 ints
    int*   blkhistA = (int*)(ws + 800016);            // raw hist (padded SB1*256 ints)
    int*   blkhistB = (int*)(ws + 1582352);           // scanned
    int*   psum     = (int*)(ws + 2364688);           // 764 ints (raw chunk sums)
    u32*   staging  = (u32*)(ws + 2367744);           // 12.8 MB (16B aligned), becomes CSR
    u16*   h1s      = (u16*)(ws + 15167744);          // 3.2 MB (16B aligned)
    u16*   h2s      = (u16*)(ws + 18367744);          // 3.2 MB (separate: gl1 reads h1s while writing h2s)

    const int B = 256;
    int gN  = (N_NODES + B - 1) / B;            // 391
    int gN2 = (N_NODES * 2 + B - 1) / B;        // 782

    // deterministic window partition + in-window node sort (zero global atomics)
    k_pcnt  <<<PNB2, B, 0, stream>>>(col, blkhistA);
    k_s1    <<<SB1, B, 0, stream>>>(blkhistA, psum);
    k_s3    <<<SB1, B, 0, stream>>>(blkhistA, psum, blkhistB);
    k_pwrite<<<PNB2, 512, 0, stream>>>(row, col, blkhistA, blkhistB, staging);
    k_csr   <<<NDIG, B, 0, stream>>>(staging, blkhistB, offs, dis);
    // dense pipeline (layer2 fused into gather1; softmax fused into gather2)
    k_gemm1 <<<gN, B, 0, stream>>>(x, W1, dis, h1s);
    k_gl1   <<<gN2, B, 0, stream>>>(offs, staging, dis, h1s, b1, W2, h2s);
    k_gather2<<<gN2, B, 0, stream>>>(offs, staging, dis, h2s, b2, out);
}